// Round 8
// baseline (487.028 us; speedup 1.0000x reference)
//
#include <hip/hip_runtime.h>
#include <hip/hip_bf16.h>
#include <math.h>

typedef __attribute__((ext_vector_type(8))) short bf16x8;
typedef __attribute__((ext_vector_type(4))) float f32x4;
typedef __attribute__((ext_vector_type(16))) float f32x16;
typedef __attribute__((ext_vector_type(8))) unsigned short u16x8;
typedef __attribute__((ext_vector_type(4))) unsigned short u16x4;

static constexpr int B = 4, S = 2048, D = 2048, H = 16, DH = 128;
static constexpr int N3 = 3 * D;   // 6144
static constexpr int M = B * S;    // 8192

__device__ __forceinline__ unsigned short f2bf(float f) {
  unsigned u = __float_as_uint(f);
  u += 0x7fffu + ((u >> 16) & 1u);
  return (unsigned short)(u >> 16);
}
__device__ __forceinline__ float bf2f(unsigned short b) {
  return __uint_as_float(((unsigned)b) << 16);
}

// ---------------- elementwise f32 -> bf16 convert (vectorized) ----------------
__global__ __launch_bounds__(256) void cvt_kernel(const float* __restrict__ in,
                                                  unsigned short* __restrict__ out) {
  size_t i = (size_t)blockIdx.x * 256 + threadIdx.x;
  f32x4 v = *(const f32x4*)(in + i * 4);
  u16x4 o;
  o[0] = f2bf(v[0]); o[1] = f2bf(v[1]); o[2] = f2bf(v[2]); o[3] = f2bf(v[3]);
  *(u16x4*)(out + i * 4) = o;
}

// ---------------- tiled transpose-convert: W (K,N) f32 -> WT (N,K) bf16 ----------------
__global__ __launch_bounds__(256) void transpose_kernel(const float* __restrict__ W,
                                                        unsigned short* __restrict__ WT,
                                                        int K, int N) {
  __shared__ float t[32][33];
  int tx = threadIdx.x, ty = threadIdx.y;
  int n0 = blockIdx.x * 32, k0 = blockIdx.y * 32;
#pragma unroll
  for (int i = 0; i < 4; i++)
    t[ty + i * 8][tx] = W[(size_t)(k0 + ty + i * 8) * N + n0 + tx];
  __syncthreads();
#pragma unroll
  for (int i = 0; i < 4; i++)
    WT[(size_t)(n0 + ty + i * 8) * K + k0 + tx] = f2bf(t[tx][ty + i * 8]);
}

// ---------------- async global->LDS helper ----------------
__device__ __forceinline__ void gload_lds(const void* g, void* l) {
  __builtin_amdgcn_global_load_lds((const __attribute__((address_space(1))) void*)g,
                                   (__attribute__((address_space(3))) void*)l, 16, 0, 0);
}

// ---------------- bf16 MFMA GEMM, 256x256 tile, m201 8-phase-style pipeline -----------
// BK=64, half-tile = (t,kh) = 32KB (A 16KB + B 16KB = 4 loads/thread).
// 2 LDS dbuf: A[db][Mhalf][kh][128][32] (64KB) + B same (64KB).
// 512 thr = 8 waves (2 wm x 4 wn), per-wave 128x64 output.
// 4 phases/tile = (kh,mh). Phase: {A-frags (+B-frags if mh==0) ds_read; 2 gload_lds;
//   s_barrier; lgkm(0); setprio1; 16 MFMA; setprio0; [vmcnt(8) at p1/p3]; s_barrier}
// Prefetch: 3 half-tiles in flight. p0/p1 stage (t+1,kh1) -> other dbuf (disjoint);
// p2/p3 stage (t+2,kh0) -> slot [t&1][kh0], whose reads ended before p1's barrier.
// vmcnt(8) = 2 newer halves outstanding -> 3rd-oldest landed. Epilogue 8->4->0.
template <int EPI>
__global__ __launch_bounds__(512, 1) void gemm_bt(
    const unsigned short* __restrict__ A, const unsigned short* __restrict__ Bt,
    const float* __restrict__ bias, float* __restrict__ Cf,
    unsigned short* __restrict__ Qp, unsigned short* __restrict__ Kp,
    unsigned short* __restrict__ VTp, int Nn, int nbn) {
  __shared__ __align__(16) unsigned short lds[65536];  // 128 KiB
  constexpr int NT = 32;  // K = 2048 / BK = 64
  const int tid = threadIdx.x;
  const int l = tid & 63;
  const int w = tid >> 6;
  const int lc = l & 15, lr = l >> 4;
  const int wm = w >> 2, wn = w & 3;

  // XCD-aware swizzle (nwg % 8 == 0), bm-major
  const int nwg = gridDim.x;
  const int cpx = nwg >> 3;
  const int wg = blockIdx.x;
  const int swz = (wg & 7) * cpx + (wg >> 3);
  const int bm = swz / nbn;
  const int bn = swz - bm * nbn;

  // ---- staging setup (per thread): 2 chunks (A,B) per phase ----
  const int lq = l >> 2, lg = l & 3;
  const int gsw = lg ^ ((l >> 3) & 3);  // pre-swizzled source granule
  const unsigned short* sA[2];
  const unsigned short* sB[2];
  int dA[2], dB[2];
#pragma unroll
  for (int mh = 0; mh < 2; mh++) {
    const int rowA = mh * 64 + wn * 16 + lq;               // row in A-half wm
    sA[mh] = A + (size_t)(bm * 256 + wm * 128 + rowA) * 2048 + gsw * 8;
    dA[mh] = wm * 8192 + rowA * 32 + lg * 8;               // + db*16384 + kh*4096
    const int rowB = (wm * 2 + (wn & 1)) * 32 + mh * 16 + lq;  // row in B-half wn>>1
    sB[mh] = Bt + (size_t)(bn * 256 + (wn >> 1) * 128 + rowB) * 2048 + gsw * 8;
    dB[mh] = 32768 + (wn >> 1) * 8192 + rowB * 32 + lg * 8;
  }

  // ---- fragment-read offsets (swizzled) ----
  const int rsw = (lr ^ ((lc >> 1) & 3)) * 8;
  const int frA = wm * 8192 + lc * 32 + rsw;               // + db*16384+kh*4096+mh*2048+mt*512
  const int frB = 32768 + (wn >> 1) * 8192 + ((wn & 1) * 64 + lc) * 32 + rsw;  // + nt*512

  f32x4 acc[8][4];
#pragma unroll
  for (int m = 0; m < 8; m++)
#pragma unroll
    for (int n = 0; n < 4; n++) acc[m][n] = (f32x4)0.f;

#define STG2(tt, skh, mh)                                                        \
  do {                                                                           \
    const int dbo_ = ((tt) & 1) * 16384 + (skh) * 4096;                          \
    const int ko_ = (tt) * 64 + (skh) * 32;                                      \
    gload_lds(sA[mh] + ko_, lds + dbo_ + dA[mh]);                                \
    gload_lds(sB[mh] + ko_, lds + dbo_ + dB[mh]);                                \
  } while (0)

  // prologue: stage half-tiles H0=(0,0), H1=(0,1), H2=(1,0); wait H0; publish
  STG2(0, 0, 0); STG2(0, 0, 1);
  STG2(0, 1, 0); STG2(0, 1, 1);
  STG2(1, 0, 0); STG2(1, 0, 1);
  __builtin_amdgcn_sched_barrier(0);
  asm volatile("s_waitcnt vmcnt(8)" ::: "memory");
  __builtin_amdgcn_s_barrier();
  __builtin_amdgcn_sched_barrier(0);

  bf16x8 bfr[4];

  // VM_: 8/4/0 -> emit that vmcnt before closing barrier; -1 -> none
#define PHASE(db_, kh_, mh_, DOSTG_, tt_, skh_, VM_)                             \
  do {                                                                           \
    bf16x8 af0, af1, af2, af3;                                                   \
    const int ab_ = (db_) * 16384 + (kh_) * 4096 + frA + (mh_) * 2048;           \
    af0 = *(const bf16x8*)(lds + ab_);                                           \
    af1 = *(const bf16x8*)(lds + ab_ + 512);                                     \
    af2 = *(const bf16x8*)(lds + ab_ + 1024);                                    \
    af3 = *(const bf16x8*)(lds + ab_ + 1536);                                    \
    if (mh_ == 0) {                                                              \
      const int bb_ = (db_) * 16384 + (kh_) * 4096 + frB;                        \
      bfr[0] = *(const bf16x8*)(lds + bb_);                                      \
      bfr[1] = *(const bf16x8*)(lds + bb_ + 512);                                \
      bfr[2] = *(const bf16x8*)(lds + bb_ + 1024);                               \
      bfr[3] = *(const bf16x8*)(lds + bb_ + 1536);                               \
    }                                                                            \
    if (DOSTG_) STG2(tt_, skh_, mh_);                                            \
    __builtin_amdgcn_sched_barrier(0);                                           \
    __builtin_amdgcn_s_barrier();                                                \
    asm volatile("s_waitcnt lgkmcnt(0)" ::: "memory");                           \
    __builtin_amdgcn_sched_barrier(0);                                           \
    __builtin_amdgcn_s_setprio(1);                                               \
    _Pragma("unroll")                                                            \
    for (int nt = 0; nt < 4; nt++) {                                             \
      acc[(mh_)*4 + 0][nt] = __builtin_amdgcn_mfma_f32_16x16x32_bf16(af0, bfr[nt], acc[(mh_)*4 + 0][nt], 0, 0, 0); \
      acc[(mh_)*4 + 1][nt] = __builtin_amdgcn_mfma_f32_16x16x32_bf16(af1, bfr[nt], acc[(mh_)*4 + 1][nt], 0, 0, 0); \
      acc[(mh_)*4 + 2][nt] = __builtin_amdgcn_mfma_f32_16x16x32_bf16(af2, bfr[nt], acc[(mh_)*4 + 2][nt], 0, 0, 0); \
      acc[(mh_)*4 + 3][nt] = __builtin_amdgcn_mfma_f32_16x16x32_bf16(af3, bfr[nt], acc[(mh_)*4 + 3][nt], 0, 0, 0); \
    }                                                                            \
    __builtin_amdgcn_s_setprio(0);                                               \
    __builtin_amdgcn_sched_barrier(0);                                           \
    if ((VM_) == 8) asm volatile("s_waitcnt vmcnt(8)" ::: "memory");             \
    else if ((VM_) == 4) asm volatile("s_waitcnt vmcnt(4)" ::: "memory");        \
    else if ((VM_) == 0) asm volatile("s_waitcnt vmcnt(0)" ::: "memory");        \
    __builtin_amdgcn_s_barrier();                                                \
    __builtin_amdgcn_sched_barrier(0);                                           \
  } while (0)

  // steady: t = 0..NT-3 (unroll 2 -> db literal)
  for (int t = 0; t < NT - 2; t += 2) {
    PHASE(0, 0, 0, true, t + 1, 1, -1);
    PHASE(0, 0, 1, true, t + 1, 1, 8);
    PHASE(0, 1, 0, true, t + 2, 0, -1);
    PHASE(0, 1, 1, true, t + 2, 0, 8);
    PHASE(1, 0, 0, true, t + 2, 1, -1);
    PHASE(1, 0, 1, true, t + 2, 1, 8);
    PHASE(1, 1, 0, true, t + 3, 0, -1);
    PHASE(1, 1, 1, true, t + 3, 0, 8);
  }
  // t = NT-2 = 30 (db=0): stage (31,kh1) only
  PHASE(0, 0, 0, true, 31, 1, -1);
  PHASE(0, 0, 1, true, 31, 1, 8);
  PHASE(0, 1, 0, false, 0, 0, -1);
  PHASE(0, 1, 1, false, 0, 0, 4);
  // t = NT-1 = 31 (db=1): no staging
  PHASE(1, 0, 0, false, 0, 0, -1);
  PHASE(1, 0, 1, false, 0, 0, 0);
  PHASE(1, 1, 0, false, 0, 0, -1);
  PHASE(1, 1, 1, false, 0, 0, -1);
#undef PHASE
#undef STG2

#pragma unroll
  for (int m = 0; m < 8; m++) {
#pragma unroll
    for (int n = 0; n < 4; n++) {
      const int col = bn * 256 + wn * 64 + n * 16 + lc;
      const float bv = bias[col];
#pragma unroll
      for (int r = 0; r < 4; r++) {
        const int row = bm * 256 + wm * 128 + (m >> 2) * 64 + (m & 3) * 16 + lr * 4 + r;
        const float v = acc[m][n][r] + bv;
        if (EPI == 0) {
          const unsigned short ob = f2bf(v);
          const int b = row >> 11, s = row & 2047;
          const int which = col >> 11, within = col & 2047;
          const int h = within >> 7, d = within & 127;
          const size_t bh = (size_t)(b * H + h);
          if (which == 0)      Qp[(bh * S + s) * DH + d] = ob;
          else if (which == 1) Kp[(bh * S + s) * DH + d] = ob;
          else                 VTp[(bh * DH + d) * S + s] = ob;
        } else {
          Cf[(size_t)row * Nn + col] = v;
        }
      }
    }
  }
}

// ---------------- RoPE in-place on (BH, S, DH) bf16, interleaved pairs ----------------
__global__ __launch_bounds__(256) void rope_kernel(unsigned short* __restrict__ T,
                                                   const float* __restrict__ cosT,
                                                   const float* __restrict__ sinT) {
  int t = blockIdx.x * 256 + threadIdx.x;
  int d8 = t & 15;
  int s = (t >> 4) & (S - 1);
  size_t off = (size_t)t * 8;
  u16x8 v = *(const u16x8*)(T + off);
  f32x4 c = *(const f32x4*)(cosT + (size_t)s * (DH / 2) + d8 * 4);
  f32x4 sn = *(const f32x4*)(sinT + (size_t)s * (DH / 2) + d8 * 4);
  u16x8 o;
#pragma unroll
  for (int j = 0; j < 4; j++) {
    float x1 = bf2f(v[2 * j]), x2 = bf2f(v[2 * j + 1]);
    o[2 * j]     = f2bf(x1 * c[j] - x2 * sn[j]);
    o[2 * j + 1] = f2bf(x1 * sn[j] + x2 * c[j]);
  }
  *(u16x8*)(T + off) = o;
}

// ---------------- flash attention v3: LDS-shared K/V tiles across 8 waves ----------
__global__ __launch_bounds__(512, 1) void attn3_kernel(
    const unsigned short* __restrict__ Q, const unsigned short* __restrict__ Kt,
    const unsigned short* __restrict__ VT, unsigned short* __restrict__ O) {
  __shared__ __align__(16) unsigned short lK[2][32 * 128];
  __shared__ __align__(16) unsigned short lV[2][128 * 40];
  const int tid = threadIdx.x;
  const int w = tid >> 6;       // wave 0..7
  const int l = tid & 63;
  const int ql = l & 31;
  const int hi = l >> 5;        // 0/1
  const int j = blockIdx.x;
  const int bh = ((j >> 3) & 7) * 8 + (j & 7);
  const int pr = j >> 6;                        // 0..3
  const int b = bh >> 4, h = bh & 15;
  const size_t base = (size_t)bh * S * DH;
  const float cl = 0.088388347648318447f * 1.44269504088896341f;  // (1/sqrt(DH))*log2e

  const int kdst = (tid * 8) ^ (((tid >> 4) & 7) << 3);
  const unsigned short* Kgb = Kt + base;
  const int vdh = tid >> 2;
  const int vc = (tid & 3) * 8;
  const int vdst = vdh * 40 + vc;
  const unsigned short* Vgr = VT + ((size_t)bh * DH + vdh) * S;
  const int sfix = (ql & 7) << 3;

  for (int half = 0; half < 2; half++) {
    const int strip = half ? 7 - pr : pr;
    const int qw0 = strip * 256 + w * 32;

    bf16x8 qf[8];
    const unsigned short* qp = Q + base + (size_t)(qw0 + ql) * DH + hi * 8;
#pragma unroll
    for (int t = 0; t < 8; t++) qf[t] = *(const bf16x8*)(qp + t * 16);

    f32x16 acc[4];
#pragma unroll
    for (int mt = 0; mt < 4; mt++) acc[mt] = (f32x16)0.f;
    float m = -INFINITY, lsum = 0.f;

    const int ntb = 8 * (strip + 1);
    const int last = 8 * strip + w;

    {
      f32x4 kr = *(const f32x4*)(Kgb + tid * 8);
      f32x4 vr = *(const f32x4*)(Vgr + vc);
      *(f32x4*)(&lK[0][kdst]) = kr;
      *(f32x4*)(&lV[0][vdst]) = vr;
      __syncthreads();
    }

    for (int kb = 0; kb < ntb; kb++) {
      const int cur = kb & 1;
      const bool more = (kb + 1 < ntb);
      f32x4 kr, vr;
      if (more) {
        kr = *(const f32x4*)(Kgb + (size_t)(kb + 1) * 4096 + tid * 8);
        vr = *(const f32x4*)(Vgr + (kb + 1) * 32 + vc);
      }
      if (kb <= last) {
        const unsigned short* kbuf = lK[cur];
        const unsigned short* vbuf = lV[cur];
        f32x16 st0 = (f32x16)0.f, st1 = (f32x16)0.f;
#pragma unroll
        for (int t = 0; t < 4; t++) {
          bf16x8 k0 = *(const bf16x8*)(kbuf + ((ql * 128 + (2 * t) * 16 + 8 * hi) ^ sfix));
          bf16x8 k1 = *(const bf16x8*)(kbuf + ((ql * 128 + (2 * t + 1) * 16 + 8 * hi) ^ sfix));
          st0 = __builtin_amdgcn_mfma_f32_32x32x16_bf16(k0, qf[2 * t], st0, 0, 0, 0);
          st1 = __builtin_amdgcn_mfma_f32_32x32x16_bf16(k1, qf[2 * t + 1], st1, 0, 0, 0);
        }
        float sv[16];
#pragma unroll
        for (int r = 0; r < 16; r++) sv[r] = st0[r] + st1[r];
        if (kb == last) {
#pragma unroll
          for (int r = 0; r < 16; r++) {
            const int klocal = (r & 3) + 8 * (r >> 2) + 4 * hi;
            sv[r] = (klocal > ql) ? -INFINITY : sv[r];
          }
        }
        float smax = sv[0];
#pragma unroll
        for (int r = 1; r < 16; r++) smax = fmaxf(smax, sv[r]);
        smax = fmaxf(smax, __shfl_xor(smax, 32));

        float fr = 1.f;
        if (!__all((smax - m) * cl <= 8.0f)) {
          const float mn = fmaxf(m, smax);
          fr = exp2f((m - mn) * cl);
          m = mn;
#pragma unroll
          for (int mt = 0; mt < 4; mt++)
#pragma unroll
            for (int r = 0; r < 16; r++) acc[mt][r] *= fr;
        }
        float p[16];
        float ps = 0.f;
#pragma unroll
        for (int r = 0; r < 16; r++) {
          p[r] = exp2f((sv[r] - m) * cl);
          ps += p[r];
        }
        lsum = lsum * fr + ps + __shfl_xor(ps, 32);

        unsigned W[8];
#pragma unroll
        for (int qd = 0; qd < 4; qd++) {
          W[2 * qd]     = (unsigned)f2bf(p[4 * qd])     | ((unsigned)f2bf(p[4 * qd + 1]) << 16);
          W[2 * qd + 1] = (unsigned)f2bf(p[4 * qd + 2]) | ((unsigned)f2bf(p[4 * qd + 3]) << 16);
        }
#pragma unroll
        for (int t = 0; t < 2; t++) {
          const unsigned s0 = hi ? W[4 * t] : W[4 * t + 2];
          const unsigned s1 = hi ? W[4 * t + 1] : W[4 * t + 3];
          const unsigned r0 = __shfl_xor((int)s0, 32);
          const unsigned r1 = __shfl_xor((int)s1, 32);
          union { unsigned u[4]; bf16x8 v; } pf;
          if (hi == 0) { pf.u[0] = W[4 * t]; pf.u[1] = W[4 * t + 1]; pf.u[2] = r0; pf.u[3] = r1; }
          else         { pf.u[0] = r0; pf.u[1] = r1; pf.u[2] = W[4 * t + 2]; pf.u[3] = W[4 * t + 3]; }
#pragma unroll
          for (int mt = 0; mt < 4; mt++) {
            const bf16x8 vf = *(const bf16x8*)(vbuf + (mt * 32 + ql) * 40 + 16 * t + 8 * hi);
            acc[mt] = __builtin_amdgcn_mfma_f32_32x32x16_bf16(vf, pf.v, acc[mt], 0, 0, 0);
          }
        }
      }
      if (more) {
        *(f32x4*)(&lK[cur ^ 1][kdst]) = kr;
        *(f32x4*)(&lV[cur ^ 1][vdst]) = vr;
      }
      __syncthreads();
    }

    const float inv = 1.f / lsum;
    const int s_glob = qw0 + ql;
    unsigned short* op = O + ((size_t)(b * S + s_glob) * H + h) * DH;
#pragma unroll
    for (int mt = 0; mt < 4; mt++)
#pragma unroll
      for (int g = 0; g < 4; g++) {
        u16x4 ov;
#pragma unroll
        for (int jj = 0; jj < 4; jj++) ov[jj] = f2bf(acc[mt][4 * g + jj] * inv);
        *(u16x4*)(op + mt * 32 + 8 * g + 4 * hi) = ov;
      }
  }
}

extern "C" void kernel_launch(void* const* d_in, const int* in_sizes, int n_in,
                              void* d_out, int out_size, void* d_ws, size_t ws_size,
                              hipStream_t stream) {
  const float* x    = (const float*)d_in[0];
  const float* cosT = (const float*)d_in[1];
  const float* sinT = (const float*)d_in[2];
  const float* Wqkv = (const float*)d_in[3];
  const float* bqkv = (const float*)d_in[4];
  const float* Wout = (const float*)d_in[5];
  const float* bout = (const float*)d_in[6];

  char* ws = (char*)d_ws;
  unsigned short* xbf   = (unsigned short*)(ws);
  unsigned short* WqkvT = (unsigned short*)(ws + ((size_t)32 << 20));
  unsigned short* WoutT = (unsigned short*)(ws + ((size_t)56 << 20));
  unsigned short* VTb   = (unsigned short*)(ws + ((size_t)64 << 20));
  unsigned short* Qb = (unsigned short*)d_out;
  unsigned short* Kb = (unsigned short*)d_out + (size_t)M * D;
  unsigned short* Ob = xbf;

  cvt_kernel<<<M * D / 1024, 256, 0, stream>>>(x, xbf);
  transpose_kernel<<<dim3(N3 / 32, D / 32), dim3(32, 8), 0, stream>>>(Wqkv, WqkvT, D, N3);
  transpose_kernel<<<dim3(D / 32, D / 32), dim3(32, 8), 0, stream>>>(Wout, WoutT, D, D);
  gemm_bt<0><<<dim3((M / 256) * (N3 / 256)), 512, 0, stream>>>(xbf, WqkvT, bqkv, nullptr,
                                                               Qb, Kb, VTb, N3, N3 / 256);
  rope_kernel<<<(B * H * S * 16) / 256, 256, 0, stream>>>(Qb, cosT, sinT);
  rope_kernel<<<(B * H * S * 16) / 256, 256, 0, stream>>>(Kb, cosT, sinT);
  attn3_kernel<<<B * H * 4, 512, 0, stream>>>(Qb, Kb, VTb, Ob);
  gemm_bt<1><<<dim3((M / 256) * (D / 256)), 512, 0, stream>>>(Ob, WoutT, bout, (float*)d_out,
                                                              nullptr, nullptr, nullptr, D, D / 256);
}